// Round 2
// baseline (433.356 us; speedup 1.0000x reference)
//
#include <hip/hip_runtime.h>

typedef __bf16 bf16x8 __attribute__((ext_vector_type(8)));
typedef float f32x4 __attribute__((ext_vector_type(4)));
typedef unsigned short u16;

// ---------- bf16 helpers (avoid __hip_bfloat16 API differences) ----------
__device__ __forceinline__ u16 f2bf(float f) {
  unsigned u = __float_as_uint(f);
  u += 0x7fffu + ((u >> 16) & 1u);   // round-to-nearest-even
  return (u16)(u >> 16);
}
__device__ __forceinline__ float bf2f(u16 h) {
  return __uint_as_float(((unsigned)h) << 16);
}

// ---------- shared NT GEMM core ----------
// D[128x128] block tile = A_nt[128 rows][K] x B_nt[128 rows][K]^T
// 4 waves in 2x2; each wave 64x64 = 4x4 fragments of 16x16x32 MFMA.
// A fragment: lane holds A[row=lane&15][k + (lane>>4)*8 ... +8]  (16B contiguous)
// B fragment: lane holds B_nt[col=lane&15][k + (lane>>4)*8 ... +8]
// D fragment: col = lane&15, row = (lane>>4)*4 + reg   (verified layout)
__device__ __forceinline__ void gemm_core(const u16* __restrict__ Ab,
                                          const u16* __restrict__ Bb,
                                          const int K, f32x4 acc[4][4]) {
  const int tid = threadIdx.x;
  const int wave = tid >> 6, lane = tid & 63;
  const int wr = (wave >> 1) << 6, wc = (wave & 1) << 6;
  const int lrow = lane & 15, lk = (lane >> 4) << 3;
  const u16* ap = Ab + (size_t)(wr + lrow) * K + lk;
  const u16* bp = Bb + (size_t)(wc + lrow) * K + lk;
  const size_t rs16 = (size_t)16 * K;
  for (int k = 0; k < K; k += 32) {
    bf16x8 a[4], b[4];
#pragma unroll
    for (int i = 0; i < 4; i++) a[i] = *(const bf16x8*)(ap + i * rs16 + k);
#pragma unroll
    for (int i = 0; i < 4; i++) b[i] = *(const bf16x8*)(bp + i * rs16 + k);
#pragma unroll
    for (int mi = 0; mi < 4; mi++)
#pragma unroll
      for (int ni = 0; ni < 4; ni++)
        acc[mi][ni] = __builtin_amdgcn_mfma_f32_16x16x32_bf16(a[mi], b[ni], acc[mi][ni], 0, 0, 0);
  }
}

#define ACC_INIT                                     \
  f32x4 acc[4][4];                                   \
  {                                                  \
    const f32x4 _z = {0.f, 0.f, 0.f, 0.f};           \
    _Pragma("unroll")                                \
    for (int _i = 0; _i < 4; _i++)                   \
      _Pragma("unroll")                              \
      for (int _j = 0; _j < 4; _j++) acc[_i][_j] = _z; \
  }

#define EPI_SETUP                                                            \
  const int tid = threadIdx.x;                                               \
  const int wave = tid >> 6;                                                 \
  const int lane = tid & 63;                                                 \
  const int mb = (blockIdx.y << 7) + ((wave >> 1) << 6) + (((lane >> 4) & 3) << 2); \
  const int nb = (blockIdx.x << 7) + ((wave & 1) << 6) + (lane & 15);

// ---------- kernel 1: weights fp32 -> bf16 ----------
__global__ void __launch_bounds__(256) k_convw(const float* __restrict__ qw,
                                               const float* __restrict__ pw,
                                               u16* __restrict__ wq, u16* __restrict__ wp) {
  const int t = blockIdx.x * 256 + threadIdx.x;  // 262144 threads
  for (int i = t; i < 786432; i += 262144) wq[i] = f2bf(qw[i]);
  wp[t] = f2bf(pw[t]);  // exactly 262144
}

// ---------- kernel 2: GroupNorm, output h[b][n][c] bf16 (transposed) ----------
__global__ void __launch_bounds__(256) k_gn(const float* __restrict__ x,
                                            const float* __restrict__ gsc,
                                            const float* __restrict__ gbi,
                                            u16* __restrict__ h) {
  const int b = blockIdx.x >> 3, g = blockIdx.x & 7;
  const size_t xoff = ((size_t)b * 512 + g * 64) * 1024;
  const float* xb = x + xoff;
  const int tid = threadIdx.x;
  const int wave = tid >> 6, lane = tid & 63;

  // pass 1: sum / sumsq over 64 ch x 1024 spatial
  float s1 = 0.f, s2 = 0.f;
  const float4* xb4 = (const float4*)xb;
  for (int i = tid; i < 16384; i += 256) {
    float4 v = xb4[i];
    s1 += v.x + v.y + v.z + v.w;
    s2 += v.x * v.x + v.y * v.y + v.z * v.z + v.w * v.w;
  }
#pragma unroll
  for (int off = 32; off; off >>= 1) { s1 += __shfl_xor(s1, off); s2 += __shfl_xor(s2, off); }
  __shared__ float red[8];
  if (lane == 0) { red[wave] = s1; red[4 + wave] = s2; }
  __syncthreads();
  const float t1 = red[0] + red[1] + red[2] + red[3];
  const float t2 = red[4] + red[5] + red[6] + red[7];
  const float mean = t1 * (1.f / 65536.f);
  const float rstd = rsqrtf(t2 * (1.f / 65536.f) - mean * mean + 1e-5f);

  // pass 2: normalize + affine, transpose 64x64 tiles through LDS, write h[b][n][c]
  __shared__ u16 tile[64][66];  // stride 132B = 33 banks -> 2-way (free)
  for (int chunk = 0; chunk < 16; chunk++) {
    const int n0 = chunk << 6;
    __syncthreads();
#pragma unroll
    for (int r = 0; r < 16; r++) {
      const int cl = (r << 2) + wave;
      const int ch = (g << 6) + cl;
      float v = xb[(size_t)cl * 1024 + n0 + lane];
      float o = (v - mean) * rstd * gsc[ch] + gbi[ch];
      tile[lane][cl] = f2bf(o);
    }
    __syncthreads();
#pragma unroll
    for (int r = 0; r < 16; r++) {
      const int nl = (r << 2) + wave;
      h[((size_t)b * 1024 + n0 + nl) * 512 + (g << 6) + lane] = tile[nl][lane];
    }
  }
}

// ---------- kernel 3: QKV GEMM  qkv[o,n] = W[o,:]·h[b][n,:] + bias ----------
// writes qT[b][n][c]*scale, kT[b][n][c], v[b][c][n]
__global__ void __launch_bounds__(256) k_qkv(const u16* __restrict__ W,
                                             const u16* __restrict__ h,
                                             const float* __restrict__ bias,
                                             u16* __restrict__ qt, u16* __restrict__ kt,
                                             u16* __restrict__ vv) {
  const int b = blockIdx.z;
  ACC_INIT
  gemm_core(W + ((size_t)blockIdx.y << 7) * 512,
            h + ((size_t)b << 19) + (((size_t)blockIdx.x << 7) * 512), 512, acc);
  EPI_SETUP
  const int sel = blockIdx.y >> 2;  // 0=q 1=k 2=v (block-uniform)
  const float scale = 0.044194173824159216f;  // 512^-0.5
  if (sel < 2) {
    u16* dst = sel ? kt : qt;
    const float sc = sel ? 1.f : scale;
    const int obase = mb - sel * 512;
#pragma unroll
    for (int mi = 0; mi < 4; mi++) {
      const int o = mb + mi * 16;
#pragma unroll
      for (int ni = 0; ni < 4; ni++) {
        const int n = nb + ni * 16;
        ushort4 pk;
        pk.x = f2bf((acc[mi][ni][0] + bias[o + 0]) * sc);
        pk.y = f2bf((acc[mi][ni][1] + bias[o + 1]) * sc);
        pk.z = f2bf((acc[mi][ni][2] + bias[o + 2]) * sc);
        pk.w = f2bf((acc[mi][ni][3] + bias[o + 3]) * sc);
        *(ushort4*)(dst + ((size_t)b * 1024 + n) * 512 + (obase + mi * 16)) = pk;
      }
    }
  } else {
#pragma unroll
    for (int mi = 0; mi < 4; mi++) {
      const int o = mb + mi * 16;
#pragma unroll
      for (int ni = 0; ni < 4; ni++) {
        const int n = nb + ni * 16;
#pragma unroll
        for (int r = 0; r < 4; r++) {
          float val = acc[mi][ni][r] + bias[o + r];
          vv[((size_t)b * 512 + (o - 1024 + r)) * 1024 + n] = f2bf(val);
        }
      }
    }
  }
}

// ---------- kernel 4: S[i,j] = qT[i,:]·kT[j,:]  (scale folded into q) ----------
__global__ void __launch_bounds__(256) k_sgemm(const u16* __restrict__ qt,
                                               const u16* __restrict__ kt,
                                               u16* __restrict__ S) {
  const int b = blockIdx.z;
  ACC_INIT
  gemm_core(qt + ((size_t)b << 19) + ((size_t)blockIdx.y << 7) * 512,
            kt + ((size_t)b << 19) + ((size_t)blockIdx.x << 7) * 512, 512, acc);
  EPI_SETUP
  const size_t base = (size_t)b << 20;
#pragma unroll
  for (int mi = 0; mi < 4; mi++)
#pragma unroll
    for (int ni = 0; ni < 4; ni++) {
      const int j = nb + ni * 16;
#pragma unroll
      for (int r = 0; r < 4; r++)
        S[base + (size_t)(mb + mi * 16 + r) * 1024 + j] = f2bf(acc[mi][ni][r]);
    }
}

// ---------- kernel 5: row softmax in place (bf16) ----------
__global__ void __launch_bounds__(256) k_softmax(u16* __restrict__ S) {
  const size_t base = (((size_t)blockIdx.y << 10) + blockIdx.x) << 10;
  const int tid = threadIdx.x;
  const int wave = tid >> 6, lane = tid & 63;
  ushort4 raw = *(const ushort4*)(S + base + tid * 4);
  float v0 = bf2f(raw.x), v1 = bf2f(raw.y), v2 = bf2f(raw.z), v3 = bf2f(raw.w);
  float m = fmaxf(fmaxf(v0, v1), fmaxf(v2, v3));
#pragma unroll
  for (int off = 32; off; off >>= 1) m = fmaxf(m, __shfl_xor(m, off));
  __shared__ float s1[4], s2[4];
  if (lane == 0) s1[wave] = m;
  __syncthreads();
  m = fmaxf(fmaxf(s1[0], s1[1]), fmaxf(s1[2], s1[3]));
  v0 = __expf(v0 - m); v1 = __expf(v1 - m); v2 = __expf(v2 - m); v3 = __expf(v3 - m);
  float s = v0 + v1 + v2 + v3;
#pragma unroll
  for (int off = 32; off; off >>= 1) s += __shfl_xor(s, off);
  if (lane == 0) s2[wave] = s;
  __syncthreads();
  s = s2[0] + s2[1] + s2[2] + s2[3];
  const float inv = 1.0f / s;
  raw.x = f2bf(v0 * inv); raw.y = f2bf(v1 * inv);
  raw.z = f2bf(v2 * inv); raw.w = f2bf(v3 * inv);
  *(ushort4*)(S + base + tid * 4) = raw;
}

// ---------- kernel 6: O[c,i] = sum_j v[c,j] P[i,j]; store ot[b][i][c] ----------
__global__ void __launch_bounds__(256) k_ogemm(const u16* __restrict__ vv,
                                               const u16* __restrict__ P,
                                               u16* __restrict__ ot) {
  const int b = blockIdx.z;
  ACC_INIT
  gemm_core(vv + ((size_t)b << 19) + ((size_t)blockIdx.y << 7) * 1024,
            P + ((size_t)b << 20) + ((size_t)blockIdx.x << 7) * 1024, 1024, acc);
  EPI_SETUP
#pragma unroll
  for (int mi = 0; mi < 4; mi++) {
    const int c = mb + mi * 16;
#pragma unroll
    for (int ni = 0; ni < 4; ni++) {
      const int i = nb + ni * 16;
      ushort4 pk;
      pk.x = f2bf(acc[mi][ni][0]);
      pk.y = f2bf(acc[mi][ni][1]);
      pk.z = f2bf(acc[mi][ni][2]);
      pk.w = f2bf(acc[mi][ni][3]);
      *(ushort4*)(ot + ((size_t)b << 19) + (size_t)i * 512 + c) = pk;
    }
  }
}

// ---------- kernel 7: out[o,n] = projW[o,:]·ot[b][n,:] + pb[o] + x ----------
__global__ void __launch_bounds__(256) k_proj(const u16* __restrict__ W,
                                              const u16* __restrict__ ot,
                                              const float* __restrict__ pb,
                                              const float* __restrict__ x,
                                              float* __restrict__ out) {
  const int b = blockIdx.z;
  ACC_INIT
  gemm_core(W + ((size_t)blockIdx.y << 7) * 512,
            ot + ((size_t)b << 19) + ((size_t)blockIdx.x << 7) * 512, 512, acc);
  EPI_SETUP
#pragma unroll
  for (int mi = 0; mi < 4; mi++) {
    const int o = mb + mi * 16;
#pragma unroll
    for (int ni = 0; ni < 4; ni++) {
      const int n = nb + ni * 16;
      const size_t base = ((size_t)b * 512 + o) * 1024 + n;
#pragma unroll
      for (int r = 0; r < 4; r++)
        out[base + (size_t)r * 1024] = acc[mi][ni][r] + pb[o + r] + x[base + (size_t)r * 1024];
    }
  }
}

// ---------- launcher ----------
extern "C" void kernel_launch(void* const* d_in, const int* in_sizes, int n_in,
                              void* d_out, int out_size, void* d_ws, size_t ws_size,
                              hipStream_t stream) {
  const float* x     = (const float*)d_in[0];
  const float* gsc   = (const float*)d_in[1];
  const float* gbi   = (const float*)d_in[2];
  const float* qkvw  = (const float*)d_in[3];
  const float* qkvb  = (const float*)d_in[4];
  const float* projw = (const float*)d_in[5];
  const float* projb = (const float*)d_in[6];
  float* out = (float*)d_out;

  char* ws = (char*)d_ws;
  u16* wq = (u16*)(ws);                    // 1536*512       = 1,572,864 B
  u16* wp = (u16*)(ws + 1572864);          // 512*512        ->   524,288 B
  u16* h  = (u16*)(ws + 2097152);          // 16*1024*512    -> 16,777,216 B
  u16* qt = (u16*)(ws + 18874368);         // 16,777,216 B
  u16* kt = (u16*)(ws + 35651584);         // 16,777,216 B
  u16* vv = (u16*)(ws + 52428864);         // 16,777,216 B
  u16* S  = (u16*)(ws + 69206080);         // 16*1024*1024*2 -> 33,554,432 B  (P in place)
  u16* ot = h;                             // h dead after k_qkv; reuse

  k_convw<<<1024, 256, 0, stream>>>(qkvw, projw, wq, wp);
  k_gn<<<128, 256, 0, stream>>>(x, gsc, gbi, h);
  k_qkv<<<dim3(8, 12, 16), 256, 0, stream>>>(wq, h, qkvb, qt, kt, vv);
  k_sgemm<<<dim3(8, 8, 16), 256, 0, stream>>>(qt, kt, S);
  k_softmax<<<dim3(1024, 16), 256, 0, stream>>>(S);
  k_ogemm<<<dim3(8, 4, 16), 256, 0, stream>>>(vv, S, ot);
  k_proj<<<dim3(8, 4, 16), 256, 0, stream>>>(wp, ot, projb, x, out);
}

// Round 6
// 293.334 us; speedup vs baseline: 1.4773x; 1.4773x over previous
//
#include <hip/hip_runtime.h>

typedef __bf16 bf16x8 __attribute__((ext_vector_type(8)));
typedef float f32x4 __attribute__((ext_vector_type(4)));
typedef unsigned short u16;

// ---------- bf16 helpers ----------
__device__ __forceinline__ u16 f2bf(float f) {
  unsigned u = __float_as_uint(f);
  u += 0x7fffu + ((u >> 16) & 1u);   // round-to-nearest-even
  return (u16)(u >> 16);
}
__device__ __forceinline__ float bf2f(u16 h) {
  return __uint_as_float(((unsigned)h) << 16);
}

// async global->LDS, 16B per lane; dest must be wave-uniform base + lane*16
#define GLOAD_LDS(g, l)                                              \
  __builtin_amdgcn_global_load_lds(                                  \
      (const __attribute__((address_space(1))) void*)(g),            \
      (__attribute__((address_space(3))) void*)(l), 16, 0, 0)

// ---------- LDS-staged NT GEMM core ----------
// D[128x128] block tile = A_nt[128 rows][K] x B_nt[128 rows][K]^T
// 4 waves 2x2, each wave 64x64 = 4x4 frags of mfma_f32_16x16x32_bf16.
// BK=64: tiles As/Bs[128 rows][64 u16] = 16KB each.
// Bank fix: row stride = 128B = exactly 32 banks -> linear reads would be
// 16-way conflicted. Swizzle: 16B slot s' = s ^ (row&7). global_load_lds
// writes linearly (base+lane*16), so the SOURCE address is inverse-swizzled
// and the ds_read applies the same XOR (both-sides involution, rule #21).
template <int K>
__device__ __forceinline__ void gemm_core_s(const u16* __restrict__ Ab,
                                            const u16* __restrict__ Bb,
                                            f32x4 acc[4][4]) {
  __shared__ __align__(16) u16 As[8192], Bs[8192];
  const int tid = threadIdx.x;
  const int wave = tid >> 6, lane = tid & 63;
  // staging: thread covers row sr(+32r), swizzled source slot
  const int sr = tid >> 3;                    // 0..31
  const int sc = ((tid ^ sr) & 7) << 3;       // (slot' ^ row&7) * 8 u16
  const u16* ag = Ab + (size_t)sr * K + sc;
  const u16* bg = Bb + (size_t)sr * K + sc;
  u16* al = As + tid * 8;                     // linear dest: byte = tid*16
  u16* bl = Bs + tid * 8;
  // fragment reads
  const int wr = (wave >> 1) << 6, wc = (wave & 1) << 6;
  const int lrow = lane & 15, klane = lane >> 4;
  const int rx = lrow & 7;
  const int ao = (wr + lrow) * 64 + ((klane ^ rx) << 3);  // u16 elements
  const int bo = (wc + lrow) * 64 + ((klane ^ rx) << 3);

  for (int k = 0; k < K; k += 64) {
    __syncthreads();                          // prev compute done
#pragma unroll
    for (int r = 0; r < 4; r++)
      GLOAD_LDS(ag + (size_t)(r * 32) * K + k, al + r * 2048);
#pragma unroll
    for (int r = 0; r < 4; r++)
      GLOAD_LDS(bg + (size_t)(r * 32) * K + k, bl + r * 2048);
    __syncthreads();                          // compiler drains vmcnt before barrier
#pragma unroll
    for (int half = 0; half < 2; half++) {
      const int xo = half << 5;               // slot bit2 == element bit5
      bf16x8 a[4], b[4];
#pragma unroll
      for (int i = 0; i < 4; i++) a[i] = *(const bf16x8*)(As + ((ao ^ xo) + (i << 10)));
#pragma unroll
      for (int i = 0; i < 4; i++) b[i] = *(const bf16x8*)(Bs + ((bo ^ xo) + (i << 10)));
#pragma unroll
      for (int mi = 0; mi < 4; mi++)
#pragma unroll
        for (int ni = 0; ni < 4; ni++)
          acc[mi][ni] = __builtin_amdgcn_mfma_f32_16x16x32_bf16(a[mi], b[ni], acc[mi][ni], 0, 0, 0);
    }
  }
}

#define ACC_INIT                                     \
  f32x4 acc[4][4];                                   \
  {                                                  \
    const f32x4 _z = {0.f, 0.f, 0.f, 0.f};           \
    _Pragma("unroll")                                \
    for (int _i = 0; _i < 4; _i++)                   \
      _Pragma("unroll")                              \
      for (int _j = 0; _j < 4; _j++) acc[_i][_j] = _z; \
  }

#define EPI_SETUP                                                            \
  const int tid = threadIdx.x;                                               \
  const int wave = tid >> 6;                                                 \
  const int lane = tid & 63;                                                 \
  const int mb = (blockIdx.y << 7) + ((wave >> 1) << 6) + (((lane >> 4) & 3) << 2); \
  const int nb = (blockIdx.x << 7) + ((wave & 1) << 6) + (lane & 15);

// ---------- kernel 1: weights fp32 -> bf16 ----------
__global__ void __launch_bounds__(256) k_convw(const float* __restrict__ qw,
                                               const float* __restrict__ pw,
                                               u16* __restrict__ wq, u16* __restrict__ wp) {
  const int t = blockIdx.x * 256 + threadIdx.x;  // 262144 threads
  for (int i = t; i < 786432; i += 262144) wq[i] = f2bf(qw[i]);
  wp[t] = f2bf(pw[t]);  // exactly 262144
}

// ---------- kernel 2: GroupNorm, output h[b][n][c] bf16 (transposed) ----------
__global__ void __launch_bounds__(256) k_gn(const float* __restrict__ x,
                                            const float* __restrict__ gsc,
                                            const float* __restrict__ gbi,
                                            u16* __restrict__ h) {
  const int b = blockIdx.x >> 3, g = blockIdx.x & 7;
  const size_t xoff = ((size_t)b * 512 + g * 64) * 1024;
  const float* xb = x + xoff;
  const int tid = threadIdx.x;
  const int wave = tid >> 6, lane = tid & 63;

  float s1 = 0.f, s2 = 0.f;
  const float4* xb4 = (const float4*)xb;
  for (int i = tid; i < 16384; i += 256) {
    float4 v = xb4[i];
    s1 += v.x + v.y + v.z + v.w;
    s2 += v.x * v.x + v.y * v.y + v.z * v.z + v.w * v.w;
  }
#pragma unroll
  for (int off = 32; off; off >>= 1) { s1 += __shfl_xor(s1, off); s2 += __shfl_xor(s2, off); }
  __shared__ float red[8];
  if (lane == 0) { red[wave] = s1; red[4 + wave] = s2; }
  __syncthreads();
  const float t1 = red[0] + red[1] + red[2] + red[3];
  const float t2 = red[4] + red[5] + red[6] + red[7];
  const float mean = t1 * (1.f / 65536.f);
  const float rstd = rsqrtf(t2 * (1.f / 65536.f) - mean * mean + 1e-5f);

  __shared__ u16 tile[64][66];  // stride 132B -> 2-way only (free)
  for (int chunk = 0; chunk < 16; chunk++) {
    const int n0 = chunk << 6;
    __syncthreads();
#pragma unroll
    for (int r = 0; r < 16; r++) {
      const int cl = (r << 2) + wave;
      const int ch = (g << 6) + cl;
      float v = xb[(size_t)cl * 1024 + n0 + lane];
      float o = (v - mean) * rstd * gsc[ch] + gbi[ch];
      tile[lane][cl] = f2bf(o);
    }
    __syncthreads();
#pragma unroll
    for (int r = 0; r < 16; r++) {
      const int nl = (r << 2) + wave;
      h[((size_t)b * 1024 + n0 + nl) * 512 + (g << 6) + lane] = tile[nl][lane];
    }
  }
}

// ---------- kernel 3: QKV GEMM ----------
__global__ void __launch_bounds__(256) k_qkv(const u16* __restrict__ W,
                                             const u16* __restrict__ h,
                                             const float* __restrict__ bias,
                                             u16* __restrict__ qt, u16* __restrict__ kt,
                                             u16* __restrict__ vv) {
  const int b = blockIdx.z;
  ACC_INIT
  gemm_core_s<512>(W + ((size_t)blockIdx.y << 7) * 512,
                   h + ((size_t)b << 19) + (((size_t)blockIdx.x << 7) * 512), acc);
  EPI_SETUP
  const int sel = blockIdx.y >> 2;  // 0=q 1=k 2=v (block-uniform)
  const float scale = 0.044194173824159216f;  // 512^-0.5
  if (sel < 2) {
    u16* dst = sel ? kt : qt;
    const float sc = sel ? 1.f : scale;
    const int obase = mb - sel * 512;
#pragma unroll
    for (int mi = 0; mi < 4; mi++) {
      const int o = mb + mi * 16;
#pragma unroll
      for (int ni = 0; ni < 4; ni++) {
        const int n = nb + ni * 16;
        ushort4 pk;
        pk.x = f2bf((acc[mi][ni][0] + bias[o + 0]) * sc);
        pk.y = f2bf((acc[mi][ni][1] + bias[o + 1]) * sc);
        pk.z = f2bf((acc[mi][ni][2] + bias[o + 2]) * sc);
        pk.w = f2bf((acc[mi][ni][3] + bias[o + 3]) * sc);
        *(ushort4*)(dst + ((size_t)b * 1024 + n) * 512 + (obase + mi * 16)) = pk;
      }
    }
  } else {
#pragma unroll
    for (int mi = 0; mi < 4; mi++) {
      const int o = mb + mi * 16;
#pragma unroll
      for (int ni = 0; ni < 4; ni++) {
        const int n = nb + ni * 16;
#pragma unroll
        for (int r = 0; r < 4; r++) {
          float val = acc[mi][ni][r] + bias[o + r];
          vv[((size_t)b * 512 + (o - 1024 + r)) * 1024 + n] = f2bf(val);
        }
      }
    }
  }
}

// ---------- kernel 4: S = q^T k ----------
__global__ void __launch_bounds__(256) k_sgemm(const u16* __restrict__ qt,
                                               const u16* __restrict__ kt,
                                               u16* __restrict__ S) {
  const int b = blockIdx.z;
  ACC_INIT
  gemm_core_s<512>(qt + ((size_t)b << 19) + ((size_t)blockIdx.y << 7) * 512,
                   kt + ((size_t)b << 19) + ((size_t)blockIdx.x << 7) * 512, acc);
  EPI_SETUP
  const size_t base = (size_t)b << 20;
#pragma unroll
  for (int mi = 0; mi < 4; mi++)
#pragma unroll
    for (int ni = 0; ni < 4; ni++) {
      const int j = nb + ni * 16;
#pragma unroll
      for (int r = 0; r < 4; r++)
        S[base + (size_t)(mb + mi * 16 + r) * 1024 + j] = f2bf(acc[mi][ni][r]);
    }
}

// ---------- kernel 5: row softmax in place (bf16) ----------
__global__ void __launch_bounds__(256) k_softmax(u16* __restrict__ S) {
  const size_t base = (((size_t)blockIdx.y << 10) + blockIdx.x) << 10;
  const int tid = threadIdx.x;
  const int wave = tid >> 6, lane = tid & 63;
  ushort4 raw = *(const ushort4*)(S + base + tid * 4);
  float v0 = bf2f(raw.x), v1 = bf2f(raw.y), v2 = bf2f(raw.z), v3 = bf2f(raw.w);
  float m = fmaxf(fmaxf(v0, v1), fmaxf(v2, v3));
#pragma unroll
  for (int off = 32; off; off >>= 1) m = fmaxf(m, __shfl_xor(m, off));
  __shared__ float s1[4], s2[4];
  if (lane == 0) s1[wave] = m;
  __syncthreads();
  m = fmaxf(fmaxf(s1[0], s1[1]), fmaxf(s1[2], s1[3]));
  v0 = __expf(v0 - m); v1 = __expf(v1 - m); v2 = __expf(v2 - m); v3 = __expf(v3 - m);
  float s = v0 + v1 + v2 + v3;
#pragma unroll
  for (int off = 32; off; off >>= 1) s += __shfl_xor(s, off);
  if (lane == 0) s2[wave] = s;
  __syncthreads();
  s = s2[0] + s2[1] + s2[2] + s2[3];
  const float inv = 1.0f / s;
  raw.x = f2bf(v0 * inv); raw.y = f2bf(v1 * inv);
  raw.z = f2bf(v2 * inv); raw.w = f2bf(v3 * inv);
  *(ushort4*)(S + base + tid * 4) = raw;
}

// ---------- kernel 6: O[c,i] = sum_j v[c,j] P[i,j]; store ot[b][i][c] ----------
__global__ void __launch_bounds__(256) k_ogemm(const u16* __restrict__ vv,
                                               const u16* __restrict__ P,
                                               u16* __restrict__ ot) {
  const int b = blockIdx.z;
  ACC_INIT
  gemm_core_s<1024>(vv + ((size_t)b << 19) + ((size_t)blockIdx.y << 7) * 1024,
                    P + ((size_t)b << 20) + ((size_t)blockIdx.x << 7) * 1024, acc);
  EPI_SETUP
#pragma unroll
  for (int mi = 0; mi < 4; mi++) {
    const int c = mb + mi * 16;
#pragma unroll
    for (int ni = 0; ni < 4; ni++) {
      const int i = nb + ni * 16;
      ushort4 pk;
      pk.x = f2bf(acc[mi][ni][0]);
      pk.y = f2bf(acc[mi][ni][1]);
      pk.z = f2bf(acc[mi][ni][2]);
      pk.w = f2bf(acc[mi][ni][3]);
      *(ushort4*)(ot + ((size_t)b << 19) + (size_t)i * 512 + c) = pk;
    }
  }
}

// ---------- kernel 7: out = projW·ot + pb + x ----------
__global__ void __launch_bounds__(256) k_proj(const u16* __restrict__ W,
                                              const u16* __restrict__ ot,
                                              const float* __restrict__ pb,
                                              const float* __restrict__ x,
                                              float* __restrict__ out) {
  const int b = blockIdx.z;
  ACC_INIT
  gemm_core_s<512>(W + ((size_t)blockIdx.y << 7) * 512,
                   ot + ((size_t)b << 19) + ((size_t)blockIdx.x << 7) * 512, acc);
  EPI_SETUP
#pragma unroll
  for (int mi = 0; mi < 4; mi++) {
    const int o = mb + mi * 16;
#pragma unroll
    for (int ni = 0; ni < 4; ni++) {
      const int n = nb + ni * 16;
      const size_t base = ((size_t)b * 512 + o) * 1024 + n;
#pragma unroll
      for (int r = 0; r < 4; r++)
        out[base + (size_t)r * 1024] = acc[mi][ni][r] + pb[o + r] + x[base + (size_t)r * 1024];
    }
  }
}

// ---------- launcher ----------
extern "C" void kernel_launch(void* const* d_in, const int* in_sizes, int n_in,
                              void* d_out, int out_size, void* d_ws, size_t ws_size,
                              hipStream_t stream) {
  const float* x     = (const float*)d_in[0];
  const float* gsc   = (const float*)d_in[1];
  const float* gbi   = (const float*)d_in[2];
  const float* qkvw  = (const float*)d_in[3];
  const float* qkvb  = (const float*)d_in[4];
  const float* projw = (const float*)d_in[5];
  const float* projb = (const float*)d_in[6];
  float* out = (float*)d_out;

  char* ws = (char*)d_ws;
  u16* wq = (u16*)(ws);                    // 1536*512       = 1,572,864 B
  u16* wp = (u16*)(ws + 1572864);          // 512*512        ->   524,288 B
  u16* h  = (u16*)(ws + 2097152);          // 16*1024*512    -> 16,777,216 B
  u16* qt = (u16*)(ws + 18874368);         // 16,777,216 B
  u16* kt = (u16*)(ws + 35651584);         // 16,777,216 B
  u16* vv = (u16*)(ws + 52428864);         // 16,777,216 B
  u16* S  = (u16*)(ws + 69206080);         // 33,554,432 B (P in place)
  u16* ot = h;                             // h dead after k_qkv; reuse

  k_convw<<<1024, 256, 0, stream>>>(qkvw, projw, wq, wp);
  k_gn<<<128, 256, 0, stream>>>(x, gsc, gbi, h);
  k_qkv<<<dim3(8, 12, 16), 256, 0, stream>>>(wq, h, qkvb, qt, kt, vv);
  k_sgemm<<<dim3(8, 8, 16), 256, 0, stream>>>(qt, kt, S);
  k_softmax<<<dim3(1024, 16), 256, 0, stream>>>(S);
  k_ogemm<<<dim3(8, 4, 16), 256, 0, stream>>>(vv, S, ot);
  k_proj<<<dim3(8, 4, 16), 256, 0, stream>>>(wp, ot, projb, x, out);
}

// Round 8
// 268.453 us; speedup vs baseline: 1.6143x; 1.0927x over previous
//
#include <hip/hip_runtime.h>

typedef __bf16 bf16x8 __attribute__((ext_vector_type(8)));
typedef float f32x4 __attribute__((ext_vector_type(4)));
typedef unsigned short u16;

// ---------- bf16 helpers ----------
__device__ __forceinline__ u16 f2bf(float f) {
  unsigned u = __float_as_uint(f);
  u += 0x7fffu + ((u >> 16) & 1u);   // round-to-nearest-even
  return (u16)(u >> 16);
}
__device__ __forceinline__ float bf2f(u16 h) {
  return __uint_as_float(((unsigned)h) << 16);
}

// async global->LDS, 16B per lane; dest must be wave-uniform base + lane*16
#define GLOAD_LDS(g, l)                                              \
  __builtin_amdgcn_global_load_lds(                                  \
      (const __attribute__((address_space(1))) void*)(g),            \
      (__attribute__((address_space(3))) void*)(l), 16, 0, 0)

// ---------- 2-phase double-buffered LDS-staged NT GEMM core (T3 minimum) ----
// D[128x128] = A_nt[128][K] x B_nt[128][K]^T. 4 waves 2x2, each 64x64.
// BK=64: As/Bs = 2 x [128][64 u16] = 16KB per buf per matrix, 64KB total.
// Swizzle (rule #21 both-sides): LDS slot s' of row r holds global 16B-slot
// s'^(r&7); staging pre-swizzles the GLOBAL source, ds_read XORs the same.
// Schedule per K-step: STAGE(next buf) -> compute(cur buf) -> barrier -> swap.
// Loads fly during the 32-MFMA compute phase (T3); barrier drains them.
template <int K>
__device__ __forceinline__ void gemm_core_s(const u16* __restrict__ Ab,
                                            const u16* __restrict__ Bb,
                                            f32x4 acc[4][4]) {
  __shared__ __align__(16) u16 As[2][8192], Bs[2][8192];
  const int tid = threadIdx.x;
  const int wave = tid >> 6, lane = tid & 63;
  // staging: thread covers rows sr, sr+32, sr+64, sr+96; swizzled source slot
  const int sr = tid >> 3;                    // 0..31
  const int sc = ((tid ^ sr) & 7) << 3;       // (slot' ^ row&7) * 8 u16
  const u16* ag = Ab + (size_t)sr * K + sc;
  const u16* bg = Bb + (size_t)sr * K + sc;
  const int ldst = tid * 8;                   // linear dest: byte = tid*16
  // fragment read offsets (within a 8192-u16 tile)
  const int wr = (wave >> 1) << 6, wc = (wave & 1) << 6;
  const int lrow = lane & 15, klane = lane >> 4;
  const int rx = lrow & 7;
  const int ao = (wr + lrow) * 64 + ((klane ^ rx) << 3);
  const int bo = (wc + lrow) * 64 + ((klane ^ rx) << 3);

  const u16 *a_cur = As[0] + ldst, *a_nxt = As[1] + ldst;  // stage dests
  const u16 *b_cur = Bs[0] + ldst, *b_nxt = Bs[1] + ldst;
  const u16 *ar = As[0], *br = Bs[0];                      // read bases
  const u16 *an = As[1], *bn = Bs[1];

  // prologue: stage k=0 into buf0
#pragma unroll
  for (int r = 0; r < 4; r++) GLOAD_LDS(ag + (size_t)(r * 32) * K, a_cur + r * 2048);
#pragma unroll
  for (int r = 0; r < 4; r++) GLOAD_LDS(bg + (size_t)(r * 32) * K, b_cur + r * 2048);
  __syncthreads();                            // drains vmcnt before first use

  for (int k = 64; k < K; k += 64) {
    // stage next tile into the other buffer (loads overlap compute below)
#pragma unroll
    for (int r = 0; r < 4; r++) GLOAD_LDS(ag + (size_t)(r * 32) * K + k, a_nxt + r * 2048);
#pragma unroll
    for (int r = 0; r < 4; r++) GLOAD_LDS(bg + (size_t)(r * 32) * K + k, b_nxt + r * 2048);
    // compute current buffer
#pragma unroll
    for (int half = 0; half < 2; half++) {
      const int xo = half << 5;               // k-half flips slot bit2 (elem bit5)
      bf16x8 a[4], b[4];
#pragma unroll
      for (int i = 0; i < 4; i++) a[i] = *(const bf16x8*)(ar + ((ao ^ xo) + (i << 10)));
#pragma unroll
      for (int i = 0; i < 4; i++) b[i] = *(const bf16x8*)(br + ((bo ^ xo) + (i << 10)));
#pragma unroll
      for (int mi = 0; mi < 4; mi++)
#pragma unroll
        for (int ni = 0; ni < 4; ni++)
          acc[mi][ni] = __builtin_amdgcn_mfma_f32_16x16x32_bf16(a[mi], b[ni], acc[mi][ni], 0, 0, 0);
    }
    __syncthreads();                          // next buf ready; cur free for restage
    // swap buffers
    const u16* t;
    t = a_cur; a_cur = a_nxt; a_nxt = t;
    t = b_cur; b_cur = b_nxt; b_nxt = t;
    t = ar; ar = an; an = t;
    t = br; br = bn; bn = t;
  }
  // epilogue: compute last staged tile (no barrier needed after)
#pragma unroll
  for (int half = 0; half < 2; half++) {
    const int xo = half << 5;
    bf16x8 a[4], b[4];
#pragma unroll
    for (int i = 0; i < 4; i++) a[i] = *(const bf16x8*)(ar + ((ao ^ xo) + (i << 10)));
#pragma unroll
    for (int i = 0; i < 4; i++) b[i] = *(const bf16x8*)(br + ((bo ^ xo) + (i << 10)));
#pragma unroll
    for (int mi = 0; mi < 4; mi++)
#pragma unroll
      for (int ni = 0; ni < 4; ni++)
        acc[mi][ni] = __builtin_amdgcn_mfma_f32_16x16x32_bf16(a[mi], b[ni], acc[mi][ni], 0, 0, 0);
  }
}

#define ACC_INIT                                     \
  f32x4 acc[4][4];                                   \
  {                                                  \
    const f32x4 _z = {0.f, 0.f, 0.f, 0.f};           \
    _Pragma("unroll")                                \
    for (int _i = 0; _i < 4; _i++)                   \
      _Pragma("unroll")                              \
      for (int _j = 0; _j < 4; _j++) acc[_i][_j] = _z; \
  }

#define EPI_SETUP                                                            \
  const int tid = threadIdx.x;                                               \
  const int wave = tid >> 6;                                                 \
  const int lane = tid & 63;                                                 \
  const int mb = (blockIdx.y << 7) + ((wave >> 1) << 6) + (((lane >> 4) & 3) << 2); \
  const int nb = (blockIdx.x << 7) + ((wave & 1) << 6) + (lane & 15);

// ---------- kernel 1: weights fp32 -> bf16 ----------
__global__ void __launch_bounds__(256) k_convw(const float* __restrict__ qw,
                                               const float* __restrict__ pw,
                                               u16* __restrict__ wq, u16* __restrict__ wp) {
  const int t = blockIdx.x * 256 + threadIdx.x;  // 262144 threads
  for (int i = t; i < 786432; i += 262144) wq[i] = f2bf(qw[i]);
  wp[t] = f2bf(pw[t]);  // exactly 262144
}

// ---------- kernel 2: GroupNorm, output h[b][n][c] bf16 (transposed) ----------
__global__ void __launch_bounds__(256) k_gn(const float* __restrict__ x,
                                            const float* __restrict__ gsc,
                                            const float* __restrict__ gbi,
                                            u16* __restrict__ h) {
  const int b = blockIdx.x >> 3, g = blockIdx.x & 7;
  const size_t xoff = ((size_t)b * 512 + g * 64) * 1024;
  const float* xb = x + xoff;
  const int tid = threadIdx.x;
  const int wave = tid >> 6, lane = tid & 63;

  float s1 = 0.f, s2 = 0.f;
  const float4* xb4 = (const float4*)xb;
  for (int i = tid; i < 16384; i += 256) {
    float4 v = xb4[i];
    s1 += v.x + v.y + v.z + v.w;
    s2 += v.x * v.x + v.y * v.y + v.z * v.z + v.w * v.w;
  }
#pragma unroll
  for (int off = 32; off; off >>= 1) { s1 += __shfl_xor(s1, off); s2 += __shfl_xor(s2, off); }
  __shared__ float red[8];
  if (lane == 0) { red[wave] = s1; red[4 + wave] = s2; }
  __syncthreads();
  const float t1 = red[0] + red[1] + red[2] + red[3];
  const float t2 = red[4] + red[5] + red[6] + red[7];
  const float mean = t1 * (1.f / 65536.f);
  const float rstd = rsqrtf(t2 * (1.f / 65536.f) - mean * mean + 1e-5f);

  __shared__ u16 tile[64][66];  // stride 132B -> 2-way only (free)
  for (int chunk = 0; chunk < 16; chunk++) {
    const int n0 = chunk << 6;
    __syncthreads();
#pragma unroll
    for (int r = 0; r < 16; r++) {
      const int cl = (r << 2) + wave;
      const int ch = (g << 6) + cl;
      float v = xb[(size_t)cl * 1024 + n0 + lane];
      float o = (v - mean) * rstd * gsc[ch] + gbi[ch];
      tile[lane][cl] = f2bf(o);
    }
    __syncthreads();
#pragma unroll
    for (int r = 0; r < 16; r++) {
      const int nl = (r << 2) + wave;
      h[((size_t)b * 1024 + n0 + nl) * 512 + (g << 6) + lane] = tile[nl][lane];
    }
  }
}

// ---------- kernel 3: QKV GEMM ----------
__global__ void __launch_bounds__(256) k_qkv(const u16* __restrict__ W,
                                             const u16* __restrict__ h,
                                             const float* __restrict__ bias,
                                             u16* __restrict__ qt, u16* __restrict__ kt,
                                             u16* __restrict__ vv) {
  const int b = blockIdx.z;
  ACC_INIT
  gemm_core_s<512>(W + ((size_t)blockIdx.y << 7) * 512,
                   h + ((size_t)b << 19) + (((size_t)blockIdx.x << 7) * 512), acc);
  EPI_SETUP
  const int sel = blockIdx.y >> 2;  // 0=q 1=k 2=v (block-uniform)
  const float scale = 0.044194173824159216f;  // 512^-0.5
  if (sel < 2) {
    u16* dst = sel ? kt : qt;
    const float sc = sel ? 1.f : scale;
    const int obase = mb - sel * 512;
#pragma unroll
    for (int mi = 0; mi < 4; mi++) {
      const int o = mb + mi * 16;
#pragma unroll
      for (int ni = 0; ni < 4; ni++) {
        const int n = nb + ni * 16;
        ushort4 pk;
        pk.x = f2bf((acc[mi][ni][0] + bias[o + 0]) * sc);
        pk.y = f2bf((acc[mi][ni][1] + bias[o + 1]) * sc);
        pk.z = f2bf((acc[mi][ni][2] + bias[o + 2]) * sc);
        pk.w = f2bf((acc[mi][ni][3] + bias[o + 3]) * sc);
        *(ushort4*)(dst + ((size_t)b * 1024 + n) * 512 + (obase + mi * 16)) = pk;
      }
    }
  } else {
#pragma unroll
    for (int mi = 0; mi < 4; mi++) {
      const int o = mb + mi * 16;
#pragma unroll
      for (int ni = 0; ni < 4; ni++) {
        const int n = nb + ni * 16;
#pragma unroll
        for (int r = 0; r < 4; r++) {
          float val = acc[mi][ni][r] + bias[o + r];
          vv[((size_t)b * 512 + (o - 1024 + r)) * 1024 + n] = f2bf(val);
        }
      }
    }
  }
}

// ---------- kernel 4: S = q^T k ----------
__global__ void __launch_bounds__(256) k_sgemm(const u16* __restrict__ qt,
                                               const u16* __restrict__ kt,
                                               u16* __restrict__ S) {
  const int b = blockIdx.z;
  ACC_INIT
  gemm_core_s<512>(qt + ((size_t)b << 19) + ((size_t)blockIdx.y << 7) * 512,
                   kt + ((size_t)b << 19) + ((size_t)blockIdx.x << 7) * 512, acc);
  EPI_SETUP
  const size_t base = (size_t)b << 20;
#pragma unroll
  for (int mi = 0; mi < 4; mi++)
#pragma unroll
    for (int ni = 0; ni < 4; ni++) {
      const int j = nb + ni * 16;
#pragma unroll
      for (int r = 0; r < 4; r++)
        S[base + (size_t)(mb + mi * 16 + r) * 1024 + j] = f2bf(acc[mi][ni][r]);
    }
}

// ---------- kernel 5: row softmax in place (bf16) ----------
__global__ void __launch_bounds__(256) k_softmax(u16* __restrict__ S) {
  const size_t base = (((size_t)blockIdx.y << 10) + blockIdx.x) << 10;
  const int tid = threadIdx.x;
  const int wave = tid >> 6, lane = tid & 63;
  ushort4 raw = *(const ushort4*)(S + base + tid * 4);
  float v0 = bf2f(raw.x), v1 = bf2f(raw.y), v2 = bf2f(raw.z), v3 = bf2f(raw.w);
  float m = fmaxf(fmaxf(v0, v1), fmaxf(v2, v3));
#pragma unroll
  for (int off = 32; off; off >>= 1) m = fmaxf(m, __shfl_xor(m, off));
  __shared__ float s1[4], s2[4];
  if (lane == 0) s1[wave] = m;
  __syncthreads();
  m = fmaxf(fmaxf(s1[0], s1[1]), fmaxf(s1[2], s1[3]));
  v0 = __expf(v0 - m); v1 = __expf(v1 - m); v2 = __expf(v2 - m); v3 = __expf(v3 - m);
  float s = v0 + v1 + v2 + v3;
#pragma unroll
  for (int off = 32; off; off >>= 1) s += __shfl_xor(s, off);
  if (lane == 0) s2[wave] = s;
  __syncthreads();
  s = s2[0] + s2[1] + s2[2] + s2[3];
  const float inv = 1.0f / s;
  raw.x = f2bf(v0 * inv); raw.y = f2bf(v1 * inv);
  raw.z = f2bf(v2 * inv); raw.w = f2bf(v3 * inv);
  *(ushort4*)(S + base + tid * 4) = raw;
}

// ---------- kernel 6: O[c,i] = sum_j v[c,j] P[i,j]; store ot[b][i][c] ----------
__global__ void __launch_bounds__(256) k_ogemm(const u16* __restrict__ vv,
                                               const u16* __restrict__ P,
                                               u16* __restrict__ ot) {
  const int b = blockIdx.z;
  ACC_INIT
  gemm_core_s<1024>(vv + ((size_t)b << 19) + ((size_t)blockIdx.y << 7) * 1024,
                    P + ((size_t)b << 20) + ((size_t)blockIdx.x << 7) * 1024, acc);
  EPI_SETUP
#pragma unroll
  for (int mi = 0; mi < 4; mi++) {
    const int c = mb + mi * 16;
#pragma unroll
    for (int ni = 0; ni < 4; ni++) {
      const int i = nb + ni * 16;
      ushort4 pk;
      pk.x = f2bf(acc[mi][ni][0]);
      pk.y = f2bf(acc[mi][ni][1]);
      pk.z = f2bf(acc[mi][ni][2]);
      pk.w = f2bf(acc[mi][ni][3]);
      *(ushort4*)(ot + ((size_t)b << 19) + (size_t)i * 512 + c) = pk;
    }
  }
}

// ---------- kernel 7: out = projW·ot + pb + x ----------
__global__ void __launch_bounds__(256) k_proj(const u16* __restrict__ W,
                                              const u16* __restrict__ ot,
                                              const float* __restrict__ pb,
                                              const float* __restrict__ x,
                                              float* __restrict__ out) {
  const int b = blockIdx.z;
  ACC_INIT
  gemm_core_s<512>(W + ((size_t)blockIdx.y << 7) * 512,
                   ot + ((size_t)b << 19) + ((size_t)blockIdx.x << 7) * 512, acc);
  EPI_SETUP
#pragma unroll
  for (int mi = 0; mi < 4; mi++) {
    const int o = mb + mi * 16;
#pragma unroll
    for (int ni = 0; ni < 4; ni++) {
      const int n = nb + ni * 16;
      const size_t base = ((size_t)b * 512 + o) * 1024 + n;
#pragma unroll
      for (int r = 0; r < 4; r++)
        out[base + (size_t)r * 1024] = acc[mi][ni][r] + pb[o + r] + x[base + (size_t)r * 1024];
    }
  }
}

// ---------- launcher ----------
extern "C" void kernel_launch(void* const* d_in, const int* in_sizes, int n_in,
                              void* d_out, int out_size, void* d_ws, size_t ws_size,
                              hipStream_t stream) {
  const float* x     = (const float*)d_in[0];
  const float* gsc   = (const float*)d_in[1];
  const float* gbi   = (const float*)d_in[2];
  const float* qkvw  = (const float*)d_in[3];
  const float* qkvb  = (const float*)d_in[4];
  const float* projw = (const float*)d_in[5];
  const float* projb = (const float*)d_in[6];
  float* out = (float*)d_out;

  char* ws = (char*)d_ws;
  u16* wq = (u16*)(ws);                    // 1536*512       = 1,572,864 B
  u16* wp = (u16*)(ws + 1572864);          // 512*512        ->   524,288 B
  u16* h  = (u16*)(ws + 2097152);          // 16*1024*512    -> 16,777,216 B
  u16* qt = (u16*)(ws + 18874368);         // 16,777,216 B
  u16* kt = (u16*)(ws + 35651584);         // 16,777,216 B
  u16* vv = (u16*)(ws + 52428864);         // 16,777,216 B
  u16* S  = (u16*)(ws + 69206080);         // 33,554,432 B (P in place)
  u16* ot = h;                             // h dead after k_qkv; reuse

  k_convw<<<1024, 256, 0, stream>>>(qkvw, projw, wq, wp);
  k_gn<<<128, 256, 0, stream>>>(x, gsc, gbi, h);
  k_qkv<<<dim3(8, 12, 16), 256, 0, stream>>>(wq, h, qkvb, qt, kt, vv);
  k_sgemm<<<dim3(8, 8, 16), 256, 0, stream>>>(qt, kt, S);
  k_softmax<<<dim3(1024, 16), 256, 0, stream>>>(S);
  k_ogemm<<<dim3(8, 4, 16), 256, 0, stream>>>(vv, S, ot);
  k_proj<<<dim3(8, 4, 16), 256, 0, stream>>>(wp, ot, projb, x, out);
}

// Round 10
// 250.611 us; speedup vs baseline: 1.7292x; 1.0712x over previous
//
#include <hip/hip_runtime.h>

typedef __bf16 bf16x8 __attribute__((ext_vector_type(8)));
typedef float f32x4 __attribute__((ext_vector_type(4)));
typedef unsigned short u16;

// ---------- bf16 helpers ----------
__device__ __forceinline__ u16 f2bf(float f) {
  unsigned u = __float_as_uint(f);
  u += 0x7fffu + ((u >> 16) & 1u);   // round-to-nearest-even
  return (u16)(u >> 16);
}
__device__ __forceinline__ float bf2f(u16 h) {
  return __uint_as_float(((unsigned)h) << 16);
}

// async global->LDS, 16B per lane; dest must be wave-uniform base + lane*16
#define GLOAD_LDS(g, l)                                              \
  __builtin_amdgcn_global_load_lds(                                  \
      (const __attribute__((address_space(1))) void*)(g),            \
      (__attribute__((address_space(3))) void*)(l), 16, 0, 0)

// ---------- 2-phase double-buffered LDS-staged NT GEMM core (T3 minimum) ----
// D[128x128] = A_nt[128][K] x B_nt[128][K]^T. 4 waves 2x2, each 64x64.
// BK=64: As/Bs = 2 x [128][64 u16] = 16KB per buf per matrix, 64KB total.
// Swizzle (rule #21 both-sides): LDS slot s' of row r holds global 16B-slot
// s'^(r&7); staging pre-swizzles the GLOBAL source, ds_read XORs the same.
// Schedule per K-step: STAGE(next buf) -> compute(cur buf) -> barrier -> swap.
template <int K>
__device__ __forceinline__ void gemm_core_s(const u16* __restrict__ Ab,
                                            const u16* __restrict__ Bb,
                                            f32x4 acc[4][4]) {
  __shared__ __align__(16) u16 As[2][8192], Bs[2][8192];
  const int tid = threadIdx.x;
  const int wave = tid >> 6, lane = tid & 63;
  const int sr = tid >> 3;                    // 0..31
  const int sc = ((tid ^ sr) & 7) << 3;       // (slot' ^ row&7) * 8 u16
  const u16* ag = Ab + (size_t)sr * K + sc;
  const u16* bg = Bb + (size_t)sr * K + sc;
  const int ldst = tid * 8;                   // linear dest: byte = tid*16
  const int wr = (wave >> 1) << 6, wc = (wave & 1) << 6;
  const int lrow = lane & 15, klane = lane >> 4;
  const int rx = lrow & 7;
  const int ao = (wr + lrow) * 64 + ((klane ^ rx) << 3);
  const int bo = (wc + lrow) * 64 + ((klane ^ rx) << 3);

  const u16 *a_cur = As[0] + ldst, *a_nxt = As[1] + ldst;
  const u16 *b_cur = Bs[0] + ldst, *b_nxt = Bs[1] + ldst;
  const u16 *ar = As[0], *br = Bs[0];
  const u16 *an = As[1], *bn = Bs[1];

#pragma unroll
  for (int r = 0; r < 4; r++) GLOAD_LDS(ag + (size_t)(r * 32) * K, a_cur + r * 2048);
#pragma unroll
  for (int r = 0; r < 4; r++) GLOAD_LDS(bg + (size_t)(r * 32) * K, b_cur + r * 2048);
  __syncthreads();

  for (int k = 64; k < K; k += 64) {
#pragma unroll
    for (int r = 0; r < 4; r++) GLOAD_LDS(ag + (size_t)(r * 32) * K + k, a_nxt + r * 2048);
#pragma unroll
    for (int r = 0; r < 4; r++) GLOAD_LDS(bg + (size_t)(r * 32) * K + k, b_nxt + r * 2048);
#pragma unroll
    for (int half = 0; half < 2; half++) {
      const int xo = half << 5;
      bf16x8 a[4], b[4];
#pragma unroll
      for (int i = 0; i < 4; i++) a[i] = *(const bf16x8*)(ar + ((ao ^ xo) + (i << 10)));
#pragma unroll
      for (int i = 0; i < 4; i++) b[i] = *(const bf16x8*)(br + ((bo ^ xo) + (i << 10)));
#pragma unroll
      for (int mi = 0; mi < 4; mi++)
#pragma unroll
        for (int ni = 0; ni < 4; ni++)
          acc[mi][ni] = __builtin_amdgcn_mfma_f32_16x16x32_bf16(a[mi], b[ni], acc[mi][ni], 0, 0, 0);
    }
    __syncthreads();
    const u16* t;
    t = a_cur; a_cur = a_nxt; a_nxt = t;
    t = b_cur; b_cur = b_nxt; b_nxt = t;
    t = ar; ar = an; an = t;
    t = br; br = bn; bn = t;
  }
#pragma unroll
  for (int half = 0; half < 2; half++) {
    const int xo = half << 5;
    bf16x8 a[4], b[4];
#pragma unroll
    for (int i = 0; i < 4; i++) a[i] = *(const bf16x8*)(ar + ((ao ^ xo) + (i << 10)));
#pragma unroll
    for (int i = 0; i < 4; i++) b[i] = *(const bf16x8*)(br + ((bo ^ xo) + (i << 10)));
#pragma unroll
    for (int mi = 0; mi < 4; mi++)
#pragma unroll
      for (int ni = 0; ni < 4; ni++)
        acc[mi][ni] = __builtin_amdgcn_mfma_f32_16x16x32_bf16(a[mi], b[ni], acc[mi][ni], 0, 0, 0);
  }
}

#define ACC_INIT                                     \
  f32x4 acc[4][4];                                   \
  {                                                  \
    const f32x4 _z = {0.f, 0.f, 0.f, 0.f};           \
    _Pragma("unroll")                                \
    for (int _i = 0; _i < 4; _i++)                   \
      _Pragma("unroll")                              \
      for (int _j = 0; _j < 4; _j++) acc[_i][_j] = _z; \
  }

#define EPI_SETUP                                                            \
  const int tid = threadIdx.x;                                               \
  const int wave = tid >> 6;                                                 \
  const int lane = tid & 63;                                                 \
  const int mb = (blockIdx.y << 7) + ((wave >> 1) << 6) + (((lane >> 4) & 3) << 2); \
  const int nb = (blockIdx.x << 7) + ((wave & 1) << 6) + (lane & 15);

// ---------- kernel 1: weights fp32 -> bf16 ----------
__global__ void __launch_bounds__(256) k_convw(const float* __restrict__ qw,
                                               const float* __restrict__ pw,
                                               u16* __restrict__ wq, u16* __restrict__ wp) {
  const int t = blockIdx.x * 256 + threadIdx.x;  // 262144 threads
  for (int i = t; i < 786432; i += 262144) wq[i] = f2bf(qw[i]);
  wp[t] = f2bf(pw[t]);  // exactly 262144
}

// ---------- GroupNorm stage 1: partial sums per (group, quarter) ----------
// grid 512: blk = (bg<<2)|split; each covers 16 ch x 1024 sp = 64KB contiguous
__global__ void __launch_bounds__(256) k_gn1(const float* __restrict__ x,
                                             float* __restrict__ part) {
  const int blk = blockIdx.x;
  const float4* src = (const float4*)(x + ((size_t)(blk >> 2) * 64 + (blk & 3) * 16) * 1024);
  float s1 = 0.f, s2 = 0.f;
  for (int i = threadIdx.x; i < 4096; i += 256) {
    float4 v = src[i];
    s1 += v.x + v.y + v.z + v.w;
    s2 += v.x * v.x + v.y * v.y + v.z * v.z + v.w * v.w;
  }
#pragma unroll
  for (int off = 32; off; off >>= 1) { s1 += __shfl_xor(s1, off); s2 += __shfl_xor(s2, off); }
  __shared__ float red[8];
  const int wave = threadIdx.x >> 6, lane = threadIdx.x & 63;
  if (lane == 0) { red[wave] = s1; red[4 + wave] = s2; }
  __syncthreads();
  if (threadIdx.x == 0) {
    part[blk * 2]     = red[0] + red[1] + red[2] + red[3];
    part[blk * 2 + 1] = red[4] + red[5] + red[6] + red[7];
  }
}

// ---------- GroupNorm stage 2: reduce 4 partials -> mean/rstd per group ----
__global__ void __launch_bounds__(128) k_gn1b(const float* __restrict__ part,
                                              float* __restrict__ stats) {
  const int g = threadIdx.x;  // 0..127 = b*8+grp
  const float s1 = part[g * 8 + 0] + part[g * 8 + 2] + part[g * 8 + 4] + part[g * 8 + 6];
  const float s2 = part[g * 8 + 1] + part[g * 8 + 3] + part[g * 8 + 5] + part[g * 8 + 7];
  const float mean = s1 * (1.f / 65536.f);
  const float var = s2 * (1.f / 65536.f) - mean * mean;
  stats[g * 2]     = mean;
  stats[g * 2 + 1] = rsqrtf(var + 1e-5f);
}

// ---------- GroupNorm stage 3: normalize + affine + transpose -> h[b][n][c] -
// grid 1024: x=chunk(8), y covers g(8)*b(16); each block: 64 ch x 128 spatial
__global__ void __launch_bounds__(256) k_gn2(const float* __restrict__ x,
                                             const float* __restrict__ gsc,
                                             const float* __restrict__ gbi,
                                             const float* __restrict__ stats,
                                             u16* __restrict__ h) {
  const int chunk = blockIdx.x & 7, g = (blockIdx.x >> 3) & 7, b = blockIdx.x >> 6;
  const int bg = b * 8 + g;
  const float mean = stats[bg * 2], rstd = stats[bg * 2 + 1];
  const float* xb = x + ((size_t)b * 512 + g * 64) * 1024;
  const int tid = threadIdx.x, wave = tid >> 6, lane = tid & 63;
  __shared__ u16 tile[64][66];  // stride 132B -> 2-way only (free)
#pragma unroll
  for (int half = 0; half < 2; half++) {
    const int n0 = chunk * 128 + half * 64;
    if (half) __syncthreads();  // protect tile reuse
#pragma unroll
    for (int r = 0; r < 16; r++) {
      const int cl = (r << 2) + wave;
      const int ch = (g << 6) + cl;
      float v = xb[(size_t)cl * 1024 + n0 + lane];
      tile[lane][cl] = f2bf((v - mean) * rstd * gsc[ch] + gbi[ch]);
    }
    __syncthreads();
#pragma unroll
    for (int r = 0; r < 16; r++) {
      const int nl = (r << 2) + wave;
      h[((size_t)b * 1024 + n0 + nl) * 512 + (g << 6) + lane] = tile[nl][lane];
    }
  }
}

// ---------- kernel 3: QKV GEMM ----------
__global__ void __launch_bounds__(256) k_qkv(const u16* __restrict__ W,
                                             const u16* __restrict__ h,
                                             const float* __restrict__ bias,
                                             u16* __restrict__ qt, u16* __restrict__ kt,
                                             u16* __restrict__ vv) {
  const int b = blockIdx.z;
  ACC_INIT
  gemm_core_s<512>(W + ((size_t)blockIdx.y << 7) * 512,
                   h + ((size_t)b << 19) + (((size_t)blockIdx.x << 7) * 512), acc);
  EPI_SETUP
  const int sel = blockIdx.y >> 2;  // 0=q 1=k 2=v (block-uniform)
  const float scale = 0.044194173824159216f;  // 512^-0.5
  if (sel < 2) {
    u16* dst = sel ? kt : qt;
    const float sc = sel ? 1.f : scale;
    const int obase = mb - sel * 512;
#pragma unroll
    for (int mi = 0; mi < 4; mi++) {
      const int o = mb + mi * 16;
#pragma unroll
      for (int ni = 0; ni < 4; ni++) {
        const int n = nb + ni * 16;
        ushort4 pk;
        pk.x = f2bf((acc[mi][ni][0] + bias[o + 0]) * sc);
        pk.y = f2bf((acc[mi][ni][1] + bias[o + 1]) * sc);
        pk.z = f2bf((acc[mi][ni][2] + bias[o + 2]) * sc);
        pk.w = f2bf((acc[mi][ni][3] + bias[o + 3]) * sc);
        *(ushort4*)(dst + ((size_t)b * 1024 + n) * 512 + (obase + mi * 16)) = pk;
      }
    }
  } else {
#pragma unroll
    for (int mi = 0; mi < 4; mi++) {
      const int o = mb + mi * 16;
#pragma unroll
      for (int ni = 0; ni < 4; ni++) {
        const int n = nb + ni * 16;
#pragma unroll
        for (int r = 0; r < 4; r++) {
          float val = acc[mi][ni][r] + bias[o + r];
          vv[((size_t)b * 512 + (o - 1024 + r)) * 1024 + n] = f2bf(val);
        }
      }
    }
  }
}

// ---------- kernel 4: S = q^T k ----------
__global__ void __launch_bounds__(256) k_sgemm(const u16* __restrict__ qt,
                                               const u16* __restrict__ kt,
                                               u16* __restrict__ S) {
  const int b = blockIdx.z;
  ACC_INIT
  gemm_core_s<512>(qt + ((size_t)b << 19) + ((size_t)blockIdx.y << 7) * 512,
                   kt + ((size_t)b << 19) + ((size_t)blockIdx.x << 7) * 512, acc);
  EPI_SETUP
  const size_t base = (size_t)b << 20;
#pragma unroll
  for (int mi = 0; mi < 4; mi++)
#pragma unroll
    for (int ni = 0; ni < 4; ni++) {
      const int j = nb + ni * 16;
#pragma unroll
      for (int r = 0; r < 4; r++)
        S[base + (size_t)(mb + mi * 16 + r) * 1024 + j] = f2bf(acc[mi][ni][r]);
    }
}

// ---------- kernel 5: row softmax in place (bf16) ----------
__global__ void __launch_bounds__(256) k_softmax(u16* __restrict__ S) {
  const size_t base = (((size_t)blockIdx.y << 10) + blockIdx.x) << 10;
  const int tid = threadIdx.x;
  const int wave = tid >> 6, lane = tid & 63;
  ushort4 raw = *(const ushort4*)(S + base + tid * 4);
  float v0 = bf2f(raw.x), v1 = bf2f(raw.y), v2 = bf2f(raw.z), v3 = bf2f(raw.w);
  float m = fmaxf(fmaxf(v0, v1), fmaxf(v2, v3));
#pragma unroll
  for (int off = 32; off; off >>= 1) m = fmaxf(m, __shfl_xor(m, off));
  __shared__ float s1[4], s2[4];
  if (lane == 0) s1[wave] = m;
  __syncthreads();
  m = fmaxf(fmaxf(s1[0], s1[1]), fmaxf(s1[2], s1[3]));
  v0 = __expf(v0 - m); v1 = __expf(v1 - m); v2 = __expf(v2 - m); v3 = __expf(v3 - m);
  float s = v0 + v1 + v2 + v3;
#pragma unroll
  for (int off = 32; off; off >>= 1) s += __shfl_xor(s, off);
  if (lane == 0) s2[wave] = s;
  __syncthreads();
  s = s2[0] + s2[1] + s2[2] + s2[3];
  const float inv = 1.0f / s;
  raw.x = f2bf(v0 * inv); raw.y = f2bf(v1 * inv);
  raw.z = f2bf(v2 * inv); raw.w = f2bf(v3 * inv);
  *(ushort4*)(S + base + tid * 4) = raw;
}

// ---------- kernel 6: O[c,i] = sum_j v[c,j] P[i,j]; store ot[b][i][c] ----------
__global__ void __launch_bounds__(256) k_ogemm(const u16* __restrict__ vv,
                                               const u16* __restrict__ P,
                                               u16* __restrict__ ot) {
  const int b = blockIdx.z;
  ACC_INIT
  gemm_core_s<1024>(vv + ((size_t)b << 19) + ((size_t)blockIdx.y << 7) * 1024,
                    P + ((size_t)b << 20) + ((size_t)blockIdx.x << 7) * 1024, acc);
  EPI_SETUP
#pragma unroll
  for (int mi = 0; mi < 4; mi++) {
    const int c = mb + mi * 16;
#pragma unroll
    for (int ni = 0; ni < 4; ni++) {
      const int i = nb + ni * 16;
      ushort4 pk;
      pk.x = f2bf(acc[mi][ni][0]);
      pk.y = f2bf(acc[mi][ni][1]);
      pk.z = f2bf(acc[mi][ni][2]);
      pk.w = f2bf(acc[mi][ni][3]);
      *(ushort4*)(ot + ((size_t)b << 19) + (size_t)i * 512 + c) = pk;
    }
  }
}

// ---------- kernel 7: out = projW·ot + pb + x ----------
__global__ void __launch_bounds__(256) k_proj(const u16* __restrict__ W,
                                              const u16* __restrict__ ot,
                                              const float* __restrict__ pb,
                                              const float* __restrict__ x,
                                              float* __restrict__ out) {
  const int b = blockIdx.z;
  ACC_INIT
  gemm_core_s<512>(W + ((size_t)blockIdx.y << 7) * 512,
                   ot + ((size_t)b << 19) + ((size_t)blockIdx.x << 7) * 512, acc);
  EPI_SETUP
#pragma unroll
  for (int mi = 0; mi < 4; mi++) {
    const int o = mb + mi * 16;
#pragma unroll
    for (int ni = 0; ni < 4; ni++) {
      const int n = nb + ni * 16;
      const size_t base = ((size_t)b * 512 + o) * 1024 + n;
#pragma unroll
      for (int r = 0; r < 4; r++)
        out[base + (size_t)r * 1024] = acc[mi][ni][r] + pb[o + r] + x[base + (size_t)r * 1024];
    }
  }
}

// ---------- launcher ----------
extern "C" void kernel_launch(void* const* d_in, const int* in_sizes, int n_in,
                              void* d_out, int out_size, void* d_ws, size_t ws_size,
                              hipStream_t stream) {
  const float* x     = (const float*)d_in[0];
  const float* gsc   = (const float*)d_in[1];
  const float* gbi   = (const float*)d_in[2];
  const float* qkvw  = (const float*)d_in[3];
  const float* qkvb  = (const float*)d_in[4];
  const float* projw = (const float*)d_in[5];
  const float* projb = (const float*)d_in[6];
  float* out = (float*)d_out;

  char* ws = (char*)d_ws;
  u16* wq = (u16*)(ws);                    // 1536*512       = 1,572,864 B
  u16* wp = (u16*)(ws + 1572864);          // 512*512        ->   524,288 B
  u16* h  = (u16*)(ws + 2097152);          // 16*1024*512    -> 16,777,216 B
  u16* qt = (u16*)(ws + 18874368);         // 16,777,216 B
  u16* kt = (u16*)(ws + 35651584);         // 16,777,216 B
  u16* vv = (u16*)(ws + 52428864);         // 16,777,216 B
  u16* S  = (u16*)(ws + 69206080);         // 33,554,432 B (P in place)
  u16* ot = h;                             // h dead after k_qkv; reuse
  // GN scratch lives in the S region (dead until k_sgemm, written every call)
  float* part  = (float*)(ws + 69206080);          // 512*2 floats = 4 KB
  float* stats = (float*)(ws + 69206080 + 8192);   // 128*2 floats = 1 KB

  k_convw<<<1024, 256, 0, stream>>>(qkvw, projw, wq, wp);
  k_gn1<<<512, 256, 0, stream>>>(x, part);
  k_gn1b<<<1, 128, 0, stream>>>(part, stats);
  k_gn2<<<1024, 256, 0, stream>>>(x, gsc, gbi, stats, h);
  k_qkv<<<dim3(8, 12, 16), 256, 0, stream>>>(wq, h, qkvb, qt, kt, vv);
  k_sgemm<<<dim3(8, 8, 16), 256, 0, stream>>>(qt, kt, S);
  k_softmax<<<dim3(1024, 16), 256, 0, stream>>>(S);
  k_ogemm<<<dim3(8, 4, 16), 256, 0, stream>>>(vv, S, ot);
  k_proj<<<dim3(8, 4, 16), 256, 0, stream>>>(wp, ot, projb, x, out);
}

// Round 11
// 235.576 us; speedup vs baseline: 1.8396x; 1.0638x over previous
//
#include <hip/hip_runtime.h>

typedef __bf16 bf16x8 __attribute__((ext_vector_type(8)));
typedef float f32x4 __attribute__((ext_vector_type(4)));
typedef unsigned short u16;

// ---------- bf16 helpers ----------
__device__ __forceinline__ u16 f2bf(float f) {
  unsigned u = __float_as_uint(f);
  u += 0x7fffu + ((u >> 16) & 1u);   // round-to-nearest-even
  return (u16)(u >> 16);
}
__device__ __forceinline__ float bf2f(u16 h) {
  return __uint_as_float(((unsigned)h) << 16);
}

// ---------- XCD-aware block swizzle (T1, bijective: nwg % 8 == 0) ----------
// HW assigns dispatch-index D to XCD D%8; remap so each XCD gets a contiguous
// chunk of logical block ids (L2 panel locality). L = (D%8)*cpx + D/8.
__device__ __forceinline__ int3 xcd_swz(int gx, int gy, int gz) {
  const int D = blockIdx.x + gx * (blockIdx.y + gy * blockIdx.z);
  const int cpx = (gx * gy * gz) >> 3;
  const int L = (D & 7) * cpx + (D >> 3);
  int3 r;
  r.x = L % gx;
  r.y = (L / gx) % gy;
  r.z = L / (gx * gy);
  return r;
}

// async global->LDS, 16B per lane; dest must be wave-uniform base + lane*16
#define GLOAD_LDS(g, l)                                              \
  __builtin_amdgcn_global_load_lds(                                  \
      (const __attribute__((address_space(1))) void*)(g),            \
      (__attribute__((address_space(3))) void*)(l), 16, 0, 0)

// ---------- 2-phase double-buffered LDS-staged NT GEMM core (T3 minimum) ----
// D[128x128] = A_nt[128][K] x B_nt[128][K]^T. 4 waves 2x2, each 64x64.
// BK=64: As/Bs = 2 x [128][64 u16] = 16KB per buf per matrix, 64KB total.
// Swizzle (rule #21 both-sides): LDS slot s' of row r holds global 16B-slot
// s'^(r&7); staging pre-swizzles the GLOBAL source, ds_read XORs the same.
// Schedule per K-step: STAGE(next buf) -> compute(cur buf) -> barrier -> swap.
template <int K>
__device__ __forceinline__ void gemm_core_s(const u16* __restrict__ Ab,
                                            const u16* __restrict__ Bb,
                                            f32x4 acc[4][4]) {
  __shared__ __align__(16) u16 As[2][8192], Bs[2][8192];
  const int tid = threadIdx.x;
  const int wave = tid >> 6, lane = tid & 63;
  const int sr = tid >> 3;                    // 0..31
  const int sc = ((tid ^ sr) & 7) << 3;       // (slot' ^ row&7) * 8 u16
  const u16* ag = Ab + (size_t)sr * K + sc;
  const u16* bg = Bb + (size_t)sr * K + sc;
  const int ldst = tid * 8;                   // linear dest: byte = tid*16
  const int wr = (wave >> 1) << 6, wc = (wave & 1) << 6;
  const int lrow = lane & 15, klane = lane >> 4;
  const int rx = lrow & 7;
  const int ao = (wr + lrow) * 64 + ((klane ^ rx) << 3);
  const int bo = (wc + lrow) * 64 + ((klane ^ rx) << 3);

  const u16 *a_cur = As[0] + ldst, *a_nxt = As[1] + ldst;
  const u16 *b_cur = Bs[0] + ldst, *b_nxt = Bs[1] + ldst;
  const u16 *ar = As[0], *br = Bs[0];
  const u16 *an = As[1], *bn = Bs[1];

#pragma unroll
  for (int r = 0; r < 4; r++) GLOAD_LDS(ag + (size_t)(r * 32) * K, a_cur + r * 2048);
#pragma unroll
  for (int r = 0; r < 4; r++) GLOAD_LDS(bg + (size_t)(r * 32) * K, b_cur + r * 2048);
  __syncthreads();

  for (int k = 64; k < K; k += 64) {
#pragma unroll
    for (int r = 0; r < 4; r++) GLOAD_LDS(ag + (size_t)(r * 32) * K + k, a_nxt + r * 2048);
#pragma unroll
    for (int r = 0; r < 4; r++) GLOAD_LDS(bg + (size_t)(r * 32) * K + k, b_nxt + r * 2048);
#pragma unroll
    for (int half = 0; half < 2; half++) {
      const int xo = half << 5;
      bf16x8 a[4], b[4];
#pragma unroll
      for (int i = 0; i < 4; i++) a[i] = *(const bf16x8*)(ar + ((ao ^ xo) + (i << 10)));
#pragma unroll
      for (int i = 0; i < 4; i++) b[i] = *(const bf16x8*)(br + ((bo ^ xo) + (i << 10)));
#pragma unroll
      for (int mi = 0; mi < 4; mi++)
#pragma unroll
        for (int ni = 0; ni < 4; ni++)
          acc[mi][ni] = __builtin_amdgcn_mfma_f32_16x16x32_bf16(a[mi], b[ni], acc[mi][ni], 0, 0, 0);
    }
    __syncthreads();
    const u16* t;
    t = a_cur; a_cur = a_nxt; a_nxt = t;
    t = b_cur; b_cur = b_nxt; b_nxt = t;
    t = ar; ar = an; an = t;
    t = br; br = bn; bn = t;
  }
#pragma unroll
  for (int half = 0; half < 2; half++) {
    const int xo = half << 5;
    bf16x8 a[4], b[4];
#pragma unroll
    for (int i = 0; i < 4; i++) a[i] = *(const bf16x8*)(ar + ((ao ^ xo) + (i << 10)));
#pragma unroll
    for (int i = 0; i < 4; i++) b[i] = *(const bf16x8*)(br + ((bo ^ xo) + (i << 10)));
#pragma unroll
    for (int mi = 0; mi < 4; mi++)
#pragma unroll
      for (int ni = 0; ni < 4; ni++)
        acc[mi][ni] = __builtin_amdgcn_mfma_f32_16x16x32_bf16(a[mi], b[ni], acc[mi][ni], 0, 0, 0);
  }
}

#define ACC_INIT                                     \
  f32x4 acc[4][4];                                   \
  {                                                  \
    const f32x4 _z = {0.f, 0.f, 0.f, 0.f};           \
    _Pragma("unroll")                                \
    for (int _i = 0; _i < 4; _i++)                   \
      _Pragma("unroll")                              \
      for (int _j = 0; _j < 4; _j++) acc[_i][_j] = _z; \
  }

#define EPI_SETUP(BX, BY)                                                    \
  const int tid = threadIdx.x;                                               \
  const int wave = tid >> 6;                                                 \
  const int lane = tid & 63;                                                 \
  const int mb = ((BY) << 7) + ((wave >> 1) << 6) + (((lane >> 4) & 3) << 2); \
  const int nb = ((BX) << 7) + ((wave & 1) << 6) + (lane & 15);

// ---------- GroupNorm stage 1 + weight conversion ----------
// grid 512: blk = (bg<<2)|split; each covers 16 ch x 1024 sp = 64KB contiguous
// Also converts qkv/proj weights fp32->bf16 (independent work, grid-stride).
__global__ void __launch_bounds__(256) k_gn1(const float* __restrict__ x,
                                             const float* __restrict__ qw,
                                             const float* __restrict__ pw,
                                             float* __restrict__ part,
                                             u16* __restrict__ wq,
                                             u16* __restrict__ wp) {
  const int blk = blockIdx.x;
  const float4* src = (const float4*)(x + ((size_t)(blk >> 2) * 64 + (blk & 3) * 16) * 1024);
  float s1 = 0.f, s2 = 0.f;
  for (int i = threadIdx.x; i < 4096; i += 256) {
    float4 v = src[i];
    s1 += v.x + v.y + v.z + v.w;
    s2 += v.x * v.x + v.y * v.y + v.z * v.z + v.w * v.w;
  }
#pragma unroll
  for (int off = 32; off; off >>= 1) { s1 += __shfl_xor(s1, off); s2 += __shfl_xor(s2, off); }
  __shared__ float red[8];
  const int wave = threadIdx.x >> 6, lane = threadIdx.x & 63;
  if (lane == 0) { red[wave] = s1; red[4 + wave] = s2; }
  __syncthreads();
  if (threadIdx.x == 0) {
    part[blk * 2]     = red[0] + red[1] + red[2] + red[3];
    part[blk * 2 + 1] = red[4] + red[5] + red[6] + red[7];
  }
  // folded weight conversion (independent of the reduction above)
  const int gtid = blk * 256 + threadIdx.x;   // 0..131071
  for (int i = gtid; i < 786432; i += 131072) wq[i] = f2bf(qw[i]);
  for (int i = gtid; i < 262144; i += 131072) wp[i] = f2bf(pw[i]);
}

// ---------- GroupNorm stage 2: stats (inline) + normalize + transpose ------
// grid 1024: x=chunk(8), y covers g(8)*b(16); each block: 64 ch x 128 spatial
__global__ void __launch_bounds__(256) k_gn2(const float* __restrict__ x,
                                             const float* __restrict__ gsc,
                                             const float* __restrict__ gbi,
                                             const float* __restrict__ part,
                                             u16* __restrict__ h) {
  const int chunk = blockIdx.x & 7, g = (blockIdx.x >> 3) & 7, b = blockIdx.x >> 6;
  const int bg = b * 8 + g;
  // inline stats reduce (was k_gn1b): 4 partial pairs for this group
  const float s1 = part[bg * 8 + 0] + part[bg * 8 + 2] + part[bg * 8 + 4] + part[bg * 8 + 6];
  const float s2 = part[bg * 8 + 1] + part[bg * 8 + 3] + part[bg * 8 + 5] + part[bg * 8 + 7];
  const float mean = s1 * (1.f / 65536.f);
  const float rstd = rsqrtf(s2 * (1.f / 65536.f) - mean * mean + 1e-5f);
  const float* xb = x + ((size_t)b * 512 + g * 64) * 1024;
  const int tid = threadIdx.x, wave = tid >> 6, lane = tid & 63;
  __shared__ u16 tile[64][66];  // stride 132B -> 2-way only (free)
#pragma unroll
  for (int half = 0; half < 2; half++) {
    const int n0 = chunk * 128 + half * 64;
    if (half) __syncthreads();  // protect tile reuse
#pragma unroll
    for (int r = 0; r < 16; r++) {
      const int cl = (r << 2) + wave;
      const int ch = (g << 6) + cl;
      float v = xb[(size_t)cl * 1024 + n0 + lane];
      tile[lane][cl] = f2bf((v - mean) * rstd * gsc[ch] + gbi[ch]);
    }
    __syncthreads();
#pragma unroll
    for (int r = 0; r < 16; r++) {
      const int nl = (r << 2) + wave;
      h[((size_t)b * 1024 + n0 + nl) * 512 + (g << 6) + lane] = tile[nl][lane];
    }
  }
}

// ---------- kernel 3: QKV GEMM ----------
__global__ void __launch_bounds__(256) k_qkv(const u16* __restrict__ W,
                                             const u16* __restrict__ h,
                                             const float* __restrict__ bias,
                                             u16* __restrict__ qt, u16* __restrict__ kt,
                                             u16* __restrict__ vv) {
  const int3 bb = xcd_swz(8, 12, 16);
  const int b = bb.z;
  ACC_INIT
  gemm_core_s<512>(W + ((size_t)bb.y << 7) * 512,
                   h + ((size_t)b << 19) + (((size_t)bb.x << 7) * 512), acc);
  EPI_SETUP(bb.x, bb.y)
  const int sel = bb.y >> 2;  // 0=q 1=k 2=v (block-uniform)
  const float scale = 0.044194173824159216f;  // 512^-0.5
  if (sel < 2) {
    u16* dst = sel ? kt : qt;
    const float sc = sel ? 1.f : scale;
    const int obase = mb - sel * 512;
#pragma unroll
    for (int mi = 0; mi < 4; mi++) {
      const int o = mb + mi * 16;
#pragma unroll
      for (int ni = 0; ni < 4; ni++) {
        const int n = nb + ni * 16;
        ushort4 pk;
        pk.x = f2bf((acc[mi][ni][0] + bias[o + 0]) * sc);
        pk.y = f2bf((acc[mi][ni][1] + bias[o + 1]) * sc);
        pk.z = f2bf((acc[mi][ni][2] + bias[o + 2]) * sc);
        pk.w = f2bf((acc[mi][ni][3] + bias[o + 3]) * sc);
        *(ushort4*)(dst + ((size_t)b * 1024 + n) * 512 + (obase + mi * 16)) = pk;
      }
    }
  } else {
#pragma unroll
    for (int mi = 0; mi < 4; mi++) {
      const int o = mb + mi * 16;
#pragma unroll
      for (int ni = 0; ni < 4; ni++) {
        const int n = nb + ni * 16;
#pragma unroll
        for (int r = 0; r < 4; r++) {
          float val = acc[mi][ni][r] + bias[o + r];
          vv[((size_t)b * 512 + (o - 1024 + r)) * 1024 + n] = f2bf(val);
        }
      }
    }
  }
}

// ---------- kernel 4: S = q^T k ----------
__global__ void __launch_bounds__(256) k_sgemm(const u16* __restrict__ qt,
                                               const u16* __restrict__ kt,
                                               u16* __restrict__ S) {
  const int3 bb = xcd_swz(8, 8, 16);
  const int b = bb.z;
  ACC_INIT
  gemm_core_s<512>(qt + ((size_t)b << 19) + ((size_t)bb.y << 7) * 512,
                   kt + ((size_t)b << 19) + ((size_t)bb.x << 7) * 512, acc);
  EPI_SETUP(bb.x, bb.y)
  const size_t base = (size_t)b << 20;
#pragma unroll
  for (int mi = 0; mi < 4; mi++)
#pragma unroll
    for (int ni = 0; ni < 4; ni++) {
      const int j = nb + ni * 16;
#pragma unroll
      for (int r = 0; r < 4; r++)
        S[base + (size_t)(mb + mi * 16 + r) * 1024 + j] = f2bf(acc[mi][ni][r]);
    }
}

// ---------- kernel 5: row softmax in place (bf16) ----------
__global__ void __launch_bounds__(256) k_softmax(u16* __restrict__ S) {
  const size_t base = (((size_t)blockIdx.y << 10) + blockIdx.x) << 10;
  const int tid = threadIdx.x;
  const int wave = tid >> 6, lane = tid & 63;
  ushort4 raw = *(const ushort4*)(S + base + tid * 4);
  float v0 = bf2f(raw.x), v1 = bf2f(raw.y), v2 = bf2f(raw.z), v3 = bf2f(raw.w);
  float m = fmaxf(fmaxf(v0, v1), fmaxf(v2, v3));
#pragma unroll
  for (int off = 32; off; off >>= 1) m = fmaxf(m, __shfl_xor(m, off));
  __shared__ float s1[4], s2[4];
  if (lane == 0) s1[wave] = m;
  __syncthreads();
  m = fmaxf(fmaxf(s1[0], s1[1]), fmaxf(s1[2], s1[3]));
  v0 = __expf(v0 - m); v1 = __expf(v1 - m); v2 = __expf(v2 - m); v3 = __expf(v3 - m);
  float s = v0 + v1 + v2 + v3;
#pragma unroll
  for (int off = 32; off; off >>= 1) s += __shfl_xor(s, off);
  if (lane == 0) s2[wave] = s;
  __syncthreads();
  s = s2[0] + s2[1] + s2[2] + s2[3];
  const float inv = 1.0f / s;
  raw.x = f2bf(v0 * inv); raw.y = f2bf(v1 * inv);
  raw.z = f2bf(v2 * inv); raw.w = f2bf(v3 * inv);
  *(ushort4*)(S + base + tid * 4) = raw;
}

// ---------- kernel 6: O[c,i] = sum_j v[c,j] P[i,j]; store ot[b][i][c] ----------
__global__ void __launch_bounds__(256) k_ogemm(const u16* __restrict__ vv,
                                               const u16* __restrict__ P,
                                               u16* __restrict__ ot) {
  const int3 bb = xcd_swz(8, 4, 16);
  const int b = bb.z;
  ACC_INIT
  gemm_core_s<1024>(vv + ((size_t)b << 19) + ((size_t)bb.y << 7) * 1024,
                    P + ((size_t)b << 20) + ((size_t)bb.x << 7) * 1024, acc);
  EPI_SETUP(bb.x, bb.y)
#pragma unroll
  for (int mi = 0; mi < 4; mi++) {
    const int c = mb + mi * 16;
#pragma unroll
    for (int ni = 0; ni < 4; ni++) {
      const int i = nb + ni * 16;
      ushort4 pk;
      pk.x = f2bf(acc[mi][ni][0]);
      pk.y = f2bf(acc[mi][ni][1]);
      pk.z = f2bf(acc[mi][ni][2]);
      pk.w = f2bf(acc[mi][ni][3]);
      *(ushort4*)(ot + ((size_t)b << 19) + (size_t)i * 512 + c) = pk;
    }
  }
}

// ---------- kernel 7: out = projW·ot + pb + x ----------
__global__ void __launch_bounds__(256) k_proj(const u16* __restrict__ W,
                                              const u16* __restrict__ ot,
                                              const float* __restrict__ pb,
                                              const float* __restrict__ x,
                                              float* __restrict__ out) {
  const int3 bb = xcd_swz(8, 4, 16);
  const int b = bb.z;
  ACC_INIT
  gemm_core_s<512>(W + ((size_t)bb.y << 7) * 512,
                   ot + ((size_t)b << 19) + ((size_t)bb.x << 7) * 512, acc);
  EPI_SETUP(bb.x, bb.y)
#pragma unroll
  for (int mi = 0; mi < 4; mi++) {
    const int o = mb + mi * 16;
#pragma unroll
    for (int ni = 0; ni < 4; ni++) {
      const int n = nb + ni * 16;
      const size_t base = ((size_t)b * 512 + o) * 1024 + n;
#pragma unroll
      for (int r = 0; r < 4; r++)
        out[base + (size_t)r * 1024] = acc[mi][ni][r] + pb[o + r] + x[base + (size_t)r * 1024];
    }
  }
}

// ---------- launcher ----------
extern "C" void kernel_launch(void* const* d_in, const int* in_sizes, int n_in,
                              void* d_out, int out_size, void* d_ws, size_t ws_size,
                              hipStream_t stream) {
  const float* x     = (const float*)d_in[0];
  const float* gsc   = (const float*)d_in[1];
  const float* gbi   = (const float*)d_in[2];
  const float* qkvw  = (const float*)d_in[3];
  const float* qkvb  = (const float*)d_in[4];
  const float* projw = (const float*)d_in[5];
  const float* projb = (const float*)d_in[6];
  float* out = (float*)d_out;

  char* ws = (char*)d_ws;
  u16* wq = (u16*)(ws);                    // 1536*512       = 1,572,864 B
  u16* wp = (u16*)(ws + 1572864);          // 512*512        ->   524,288 B
  u16* h  = (u16*)(ws + 2097152);          // 16*1024*512    -> 16,777,216 B
  u16* qt = (u16*)(ws + 18874368);         // 16,777,216 B
  u16* kt = (u16*)(ws + 35651584);         // 16,777,216 B
  u16* vv = (u16*)(ws + 52428864);         // 16,777,216 B
  u16* S  = (u16*)(ws + 69206080);         // 33,554,432 B (P in place)
  u16* ot = h;                             // h dead after k_qkv; reuse
  // GN partials live in the S region (dead until k_sgemm, written every call)
  float* part = (float*)(ws + 69206080);   // 512*2 floats = 4 KB

  k_gn1<<<512, 256, 0, stream>>>(x, qkvw, projw, part, wq, wp);
  k_gn2<<<1024, 256, 0, stream>>>(x, gsc, gbi, part, h);
  k_qkv<<<dim3(8, 12, 16), 256, 0, stream>>>(wq, h, qkvb, qt, kt, vv);
  k_sgemm<<<dim3(8, 8, 16), 256, 0, stream>>>(qt, kt, S);
  k_softmax<<<dim3(1024, 16), 256, 0, stream>>>(S);
  k_ogemm<<<dim3(8, 4, 16), 256, 0, stream>>>(vv, S, ot);
  k_proj<<<dim3(8, 4, 16), 256, 0, stream>>>(wp, ot, projb, x, out);
}